// Round 1
// baseline (1330.293 us; speedup 1.0000x reference)
//
#include <hip/hip_runtime.h>
#include <hip/hip_bf16.h>

#define DDIM 128

// K0: y[b][d] = att1_b[d] + sum_k att1_w[d][128+k] * u2e[nodes[b]][k]
// (the u_rep half of layer 1, computed once per node instead of per edge)
__global__ __launch_bounds__(128) void node_term_kernel(
    const int* __restrict__ nodes, const float* __restrict__ u2e,
    const float* __restrict__ att1_w, const float* __restrict__ att1_b,
    float* __restrict__ y, int B)
{
  __shared__ float u_lds[8][DDIM];
  const int tid = threadIdx.x;
  const int b0 = blockIdx.x * 8;
#pragma unroll
  for (int n = 0; n < 8; ++n) {
    int b = b0 + n;
    int node = (b < B) ? nodes[b] : 0;
    u_lds[n][tid] = u2e[(long)node * DDIM + tid];
  }
  __syncthreads();
  float acc[8];
#pragma unroll
  for (int n = 0; n < 8; ++n) acc[n] = 0.f;
  const float4* w4p = (const float4*)att1_w;
  // row `tid` of att1_w, second half (cols 128..255): float4 index tid*64 + 32 + q
  for (int q = 0; q < 32; ++q) {
    float4 w = w4p[tid * 64 + 32 + q];
#pragma unroll
    for (int n = 0; n < 8; ++n) {
      acc[n] = fmaf(w.x, u_lds[n][4*q+0],
               fmaf(w.y, u_lds[n][4*q+1],
               fmaf(w.z, u_lds[n][4*q+2],
               fmaf(w.w, u_lds[n][4*q+3], acc[n]))));
    }
  }
  float bias = att1_b[tid];
#pragma unroll
  for (int n = 0; n < 8; ++n) {
    int b = b0 + n;
    if (b < B) y[(long)b * DDIM + tid] = acc[n] + bias;
  }
}

// K1: logits[e] = att3( relu( att2( relu( e_u@W1a^T + y[seg] ) ) ) )
// One edge per thread. h1[128] fully register-resident (all static indices).
// Weight addresses have no tid dependence -> scalarized to s_load streams.
__global__ __launch_bounds__(256, 2) void logits_kernel(
    const int* __restrict__ neigh_idx, const int* __restrict__ seg_ids,
    const float* __restrict__ u2e, const float* __restrict__ att1_w,
    const float* __restrict__ att2_w, const float* __restrict__ att2_b,
    const float* __restrict__ att3_w, const float* __restrict__ att3_b,
    const float* __restrict__ y, float* __restrict__ logits, int E)
{
  const int e0 = blockIdx.x * 256 + threadIdx.x;
  const int e = (e0 < E) ? e0 : (E - 1);
  const int nb  = neigh_idx[e];
  const int seg = seg_ids[e];

  float h1[DDIM];
  const float4* y4 = (const float4*)y;
#pragma unroll
  for (int q = 0; q < 32; ++q) {
    float4 v = y4[(long)seg * 32 + q];
    h1[4*q+0] = v.x; h1[4*q+1] = v.y; h1[4*q+2] = v.z; h1[4*q+3] = v.w;
  }

  const float4* u4 = (const float4*)u2e;
  for (int kt = 0; kt < 8; ++kt) {   // k in chunks of 16 over the e_u half
    float x16[16];
#pragma unroll
    for (int q = 0; q < 4; ++q) {
      float4 v = u4[(long)nb * 32 + kt * 4 + q];
      x16[4*q+0] = v.x; x16[4*q+1] = v.y; x16[4*q+2] = v.z; x16[4*q+3] = v.w;
    }
#pragma unroll
    for (int j = 0; j < 128; ++j) {
      const float* wrow = att1_w + j * 256 + kt * 16;  // uniform address
#pragma unroll
      for (int k = 0; k < 16; ++k)
        h1[j] = fmaf(wrow[k], x16[k], h1[j]);
    }
  }
#pragma unroll
  for (int j = 0; j < 128; ++j) h1[j] = fmaxf(h1[j], 0.f);

  float logit = att3_b[0];
  for (int jb = 0; jb < 16; ++jb) {  // 8 output dims of layer 2 at a time
    float acc[8];
#pragma unroll
    for (int j = 0; j < 8; ++j) acc[j] = att2_b[jb * 8 + j];
#pragma unroll
    for (int k = 0; k < DDIM; ++k) {
      float hk = h1[k];
#pragma unroll
      for (int j = 0; j < 8; ++j)
        acc[j] = fmaf(att2_w[(jb * 8 + j) * DDIM + k], hk, acc[j]);
    }
#pragma unroll
    for (int j = 0; j < 8; ++j)
      logit = fmaf(att3_w[jb * 8 + j], fmaxf(acc[j], 0.f), logit);
  }
  if (e0 < E) logits[e0] = logit;
}

// K2: per-segment softmax + attention-weighted aggregation of e_u.
// One wave (64 threads) per segment; segments are contiguous (sorted seg_ids).
__global__ __launch_bounds__(64) void softmax_agg_kernel(
    const int* __restrict__ neigh_idx, const int* __restrict__ seg_ids,
    const float* __restrict__ u2e, const float* __restrict__ logits,
    float* __restrict__ out, int B, int E)
{
  __shared__ float p_lds[1024];
  const int b = blockIdx.x;
  if (b >= B) return;
  const int tid = threadIdx.x;

  // lower_bound(seg_ids, b) and lower_bound(seg_ids, b+1)
  int lo = 0, hi = E;
  while (lo < hi) { int mid = (lo + hi) >> 1; if (seg_ids[mid] < b) lo = mid + 1; else hi = mid; }
  const int start = lo;
  hi = E;
  while (lo < hi) { int mid = (lo + hi) >> 1; if (seg_ids[mid] < b + 1) lo = mid + 1; else hi = mid; }
  const int end = lo;
  const int deg = end - start;

  float m = -3.4e38f;
  for (int i = tid; i < deg; i += 64) m = fmaxf(m, logits[start + i]);
#pragma unroll
  for (int off = 32; off; off >>= 1) m = fmaxf(m, __shfl_xor(m, off));

  float s = 0.f;
  for (int i = tid; i < deg; i += 64) s += __expf(logits[start + i] - m);
#pragma unroll
  for (int off = 32; off; off >>= 1) s += __shfl_xor(s, off);
  const float inv = (s > 0.f) ? (1.f / s) : 0.f;

  float2 acc = make_float2(0.f, 0.f);
  const float2* u2 = (const float2*)u2e;
  for (int c0 = 0; c0 < deg; c0 += 1024) {
    int cn = min(1024, deg - c0);
    __syncthreads();
    for (int i = tid; i < cn; i += 64)
      p_lds[i] = __expf(logits[start + c0 + i] - m);
    __syncthreads();
    for (int i = 0; i < cn; ++i) {
      float a = p_lds[i] * inv;
      float2 v = u2[(long)neigh_idx[start + c0 + i] * 64 + tid];
      acc.x = fmaf(a, v.x, acc.x);
      acc.y = fmaf(a, v.y, acc.y);
    }
  }
  ((float2*)out)[(long)b * 64 + tid] = acc;
}

extern "C" void kernel_launch(void* const* d_in, const int* in_sizes, int n_in,
                              void* d_out, int out_size, void* d_ws, size_t ws_size,
                              hipStream_t stream) {
  const int*   nodes     = (const int*)d_in[0];
  const int*   neigh_idx = (const int*)d_in[1];
  const int*   seg_ids   = (const int*)d_in[2];
  const float* u2e       = (const float*)d_in[3];
  const float* att1_w    = (const float*)d_in[4];
  const float* att1_b    = (const float*)d_in[5];
  const float* att2_w    = (const float*)d_in[6];
  const float* att2_b    = (const float*)d_in[7];
  const float* att3_w    = (const float*)d_in[8];
  const float* att3_b    = (const float*)d_in[9];
  const int B = in_sizes[0];
  const int E = in_sizes[1];

  float* y      = (float*)d_ws;                                    // B*128 floats
  float* logits = (float*)((char*)d_ws + (size_t)B * DDIM * 4);    // E floats

  node_term_kernel<<<(B + 7) / 8, 128, 0, stream>>>(nodes, u2e, att1_w, att1_b, y, B);
  logits_kernel<<<(E + 255) / 256, 256, 0, stream>>>(neigh_idx, seg_ids, u2e, att1_w,
                                                     att2_w, att2_b, att3_w, att3_b,
                                                     y, logits, E);
  softmax_agg_kernel<<<B, 64, 0, stream>>>(neigh_idx, seg_ids, u2e, logits,
                                           (float*)d_out, B, E);
}

// Round 2
// 117.530 us; speedup vs baseline: 11.3188x; 11.3188x over previous
//
#include <hip/hip_runtime.h>
#include <hip/hip_bf16.h>

#define DDIM 128
#define TE 128   // edges per block in logits kernel

typedef __attribute__((ext_vector_type(8))) short short8;
typedef __attribute__((ext_vector_type(4))) float f32x4;
typedef unsigned int u32;

// RNE float->bf16 (bit pattern)
static __device__ __forceinline__ unsigned short f2bf(float f) {
  u32 u = __builtin_bit_cast(u32, f);
  u += 0x7FFFu + ((u >> 16) & 1u);
  return (unsigned short)(u >> 16);
}

// LDS byte offset for (row, kbyte) with 16B XOR swizzle (row stride 256B)
#define SWZ(row, kb) ((((row) * 256) + (kb)) ^ (((row) & 7) << 4))

// K0: y[b][d] = att1_b[d] + sum_k att1_w[d][128+k] * u2e[nodes[b]][k]
__global__ __launch_bounds__(128) void node_term_kernel(
    const int* __restrict__ nodes, const float* __restrict__ u2e,
    const float* __restrict__ att1_w, const float* __restrict__ att1_b,
    float* __restrict__ y, int B)
{
  __shared__ float u_lds[8][DDIM];
  const int tid = threadIdx.x;
  const int b0 = blockIdx.x * 8;
#pragma unroll
  for (int n = 0; n < 8; ++n) {
    int b = b0 + n;
    int node = (b < B) ? nodes[b] : 0;
    u_lds[n][tid] = u2e[(long)node * DDIM + tid];
  }
  __syncthreads();
  float acc[8];
#pragma unroll
  for (int n = 0; n < 8; ++n) acc[n] = 0.f;
  const float4* w4p = (const float4*)att1_w;
  for (int q = 0; q < 32; ++q) {
    float4 w = w4p[tid * 64 + 32 + q];
#pragma unroll
    for (int n = 0; n < 8; ++n) {
      acc[n] = fmaf(w.x, u_lds[n][4*q+0],
               fmaf(w.y, u_lds[n][4*q+1],
               fmaf(w.z, u_lds[n][4*q+2],
               fmaf(w.w, u_lds[n][4*q+3], acc[n]))));
    }
  }
  float bias = att1_b[tid];
#pragma unroll
  for (int n = 0; n < 8; ++n) {
    int b = b0 + n;
    if (b < B) y[(long)b * DDIM + tid] = acc[n] + bias;
  }
}

// K1: MFMA edge MLP. Block = 256 threads (4 waves), TE=128 edges.
// Swapped orientation: D[j][e] = W[j][k] * X^T[k][e]  (A=W from LDS, B=X from LDS)
// Layer1 acc initialized with y[seg[e]][j] (per-node term incl. att1_b).
__global__ __launch_bounds__(256, 2) void logits_mfma_kernel(
    const int* __restrict__ neigh_idx, const int* __restrict__ seg_ids,
    const float* __restrict__ u2e, const float* __restrict__ att1_w,
    const float* __restrict__ att2_w, const float* __restrict__ att2_b,
    const float* __restrict__ att3_w, const float* __restrict__ att3_b,
    const float* __restrict__ y, float* __restrict__ logits, int E)
{
  extern __shared__ char smem[];
  char* xl = smem;            // 32 KB: x tile then h tile, [128 rows][256B], swizzled
  char* wl = smem + 32768;    // 32 KB: w1a then w2,    [128 rows][256B], swizzled

  const int tid = threadIdx.x;
  const int e0 = blockIdx.x * TE;

  // ---- stage x (gathered u2e rows -> bf16) and w1a (first 128 cols) ----
  const int r  = tid >> 1;           // row 0..127 (edge-local / weight row j)
  const int kh = (tid & 1) * 64;     // element offset within row
  {
    int eg = e0 + r; if (eg >= E) eg = E - 1;
    const long nb = neigh_idx[eg];
    const float4* srcx = (const float4*)(u2e + nb * DDIM + kh);
    const float4* srcw = (const float4*)(att1_w + (long)r * 2 * DDIM + kh);
#pragma unroll
    for (int c = 0; c < 8; ++c) {
      float4 v0 = srcx[c*2], v1 = srcx[c*2+1];
      u32 p[4];
      p[0] = f2bf(v0.x) | ((u32)f2bf(v0.y) << 16);
      p[1] = f2bf(v0.z) | ((u32)f2bf(v0.w) << 16);
      p[2] = f2bf(v1.x) | ((u32)f2bf(v1.y) << 16);
      p[3] = f2bf(v1.z) | ((u32)f2bf(v1.w) << 16);
      *(uint4*)(xl + SWZ(r, (tid & 1) * 128 + c * 16)) = make_uint4(p[0], p[1], p[2], p[3]);
      float4 w0 = srcw[c*2], w1 = srcw[c*2+1];
      p[0] = f2bf(w0.x) | ((u32)f2bf(w0.y) << 16);
      p[1] = f2bf(w0.z) | ((u32)f2bf(w0.w) << 16);
      p[2] = f2bf(w1.x) | ((u32)f2bf(w1.y) << 16);
      p[3] = f2bf(w1.z) | ((u32)f2bf(w1.w) << 16);
      *(uint4*)(wl + SWZ(r, (tid & 1) * 128 + c * 16)) = make_uint4(p[0], p[1], p[2], p[3]);
    }
  }

  const int wid = tid >> 6, lane = tid & 63;
  const int l15 = lane & 15, q = lane >> 4;
  const int ebase = wid * 32;

  // seg ids for this wave's two 16-edge column tiles
  int seg_et[2];
#pragma unroll
  for (int et = 0; et < 2; ++et) {
    int eg = e0 + ebase + et * 16 + l15; if (eg >= E) eg = E - 1;
    seg_et[et] = seg_ids[eg];
  }

  // acc init: D1[j][e] starts at y[seg[e]][j]   (D layout: row j=(q*4+i), col e=l15)
  f32x4 acc[8][2];
#pragma unroll
  for (int jt = 0; jt < 8; ++jt)
#pragma unroll
    for (int et = 0; et < 2; ++et) {
      const float* yr = y + (long)seg_et[et] * DDIM + jt * 16 + q * 4;
#pragma unroll
      for (int i = 0; i < 4; ++i) acc[jt][et][i] = yr[i];
    }

  __syncthreads();

  // ---- layer 1 MFMA: A = w1a rows j, B = x rows e ----
#pragma unroll
  for (int ks = 0; ks < 4; ++ks) {
    const int kb = ks * 64 + q * 16;
    short8 bx[2], aw[8];
#pragma unroll
    for (int et = 0; et < 2; ++et)
      bx[et] = *(const short8*)(xl + SWZ(ebase + et * 16 + l15, kb));
#pragma unroll
    for (int jt = 0; jt < 8; ++jt)
      aw[jt] = *(const short8*)(wl + SWZ(jt * 16 + l15, kb));
#pragma unroll
    for (int jt = 0; jt < 8; ++jt)
#pragma unroll
      for (int et = 0; et < 2; ++et)
        acc[jt][et] = __builtin_amdgcn_mfma_f32_16x16x32_bf16(aw[jt], bx[et], acc[jt][et], 0, 0, 0);
  }

  __syncthreads();  // all x reads done before h overwrites

  // ---- epilogue L1: h = relu(acc) -> bf16 -> xl rows [e][j]; stage w2 -> wl ----
#pragma unroll
  for (int jt = 0; jt < 8; ++jt)
#pragma unroll
    for (int et = 0; et < 2; ++et) {
      float h0 = fmaxf(acc[jt][et][0], 0.f), h1 = fmaxf(acc[jt][et][1], 0.f);
      float h2 = fmaxf(acc[jt][et][2], 0.f), h3 = fmaxf(acc[jt][et][3], 0.f);
      u32 p01 = f2bf(h0) | ((u32)f2bf(h1) << 16);
      u32 p23 = f2bf(h2) | ((u32)f2bf(h3) << 16);
      int row = ebase + et * 16 + l15;
      int kbyte = jt * 32 + q * 8;   // j = jt*16 + q*4 + i  -> byte j*2
      *(uint2*)(xl + SWZ(row, kbyte)) = make_uint2(p01, p23);
    }
  {
    const float4* srcw = (const float4*)(att2_w + (long)r * DDIM + kh);
#pragma unroll
    for (int c = 0; c < 8; ++c) {
      float4 w0 = srcw[c*2], w1 = srcw[c*2+1];
      u32 p0 = f2bf(w0.x) | ((u32)f2bf(w0.y) << 16);
      u32 p1 = f2bf(w0.z) | ((u32)f2bf(w0.w) << 16);
      u32 p2 = f2bf(w1.x) | ((u32)f2bf(w1.y) << 16);
      u32 p3 = f2bf(w1.z) | ((u32)f2bf(w1.w) << 16);
      *(uint4*)(wl + SWZ(r, (tid & 1) * 128 + c * 16)) = make_uint4(p0, p1, p2, p3);
    }
  }

#pragma unroll
  for (int jt = 0; jt < 8; ++jt)
#pragma unroll
    for (int et = 0; et < 2; ++et) {
      acc[jt][et][0] = 0.f; acc[jt][et][1] = 0.f; acc[jt][et][2] = 0.f; acc[jt][et][3] = 0.f;
    }

  __syncthreads();

  // ---- layer 2 MFMA: A = w2 rows j2, B = h rows e ----
#pragma unroll
  for (int ks = 0; ks < 4; ++ks) {
    const int kb = ks * 64 + q * 16;
    short8 bx[2], aw[8];
#pragma unroll
    for (int et = 0; et < 2; ++et)
      bx[et] = *(const short8*)(xl + SWZ(ebase + et * 16 + l15, kb));
#pragma unroll
    for (int jt = 0; jt < 8; ++jt)
      aw[jt] = *(const short8*)(wl + SWZ(jt * 16 + l15, kb));
#pragma unroll
    for (int jt = 0; jt < 8; ++jt)
#pragma unroll
      for (int et = 0; et < 2; ++et)
        acc[jt][et] = __builtin_amdgcn_mfma_f32_16x16x32_bf16(aw[jt], bx[et], acc[jt][et], 0, 0, 0);
  }

  // ---- layer 3: logit[e] = sum_j2 relu(h2[j2][e] + b2[j2]) * w3[j2] ----
  float plog[2] = {0.f, 0.f};
#pragma unroll
  for (int jt = 0; jt < 8; ++jt)
#pragma unroll
    for (int i = 0; i < 4; ++i) {
      int j2 = jt * 16 + q * 4 + i;
      float b2 = att2_b[j2];
      float w3 = att3_w[j2];
#pragma unroll
      for (int et = 0; et < 2; ++et)
        plog[et] = fmaf(fmaxf(acc[jt][et][i] + b2, 0.f), w3, plog[et]);
    }
  float b3 = att3_b[0];
#pragma unroll
  for (int et = 0; et < 2; ++et) {
    float v = plog[et];
    v += __shfl_xor(v, 16);
    v += __shfl_xor(v, 32);
    if (q == 0) {
      int eg = e0 + ebase + et * 16 + l15;
      if (eg < E) logits[eg] = v + b3;
    }
  }
}

// K2: per-segment softmax + attention-weighted aggregation of e_u.
__global__ __launch_bounds__(64) void softmax_agg_kernel(
    const int* __restrict__ neigh_idx, const int* __restrict__ seg_ids,
    const float* __restrict__ u2e, const float* __restrict__ logits,
    float* __restrict__ out, int B, int E)
{
  __shared__ float p_lds[1024];
  const int b = blockIdx.x;
  if (b >= B) return;
  const int tid = threadIdx.x;

  int lo = 0, hi = E;
  while (lo < hi) { int mid = (lo + hi) >> 1; if (seg_ids[mid] < b) lo = mid + 1; else hi = mid; }
  const int start = lo;
  hi = E;
  while (lo < hi) { int mid = (lo + hi) >> 1; if (seg_ids[mid] < b + 1) lo = mid + 1; else hi = mid; }
  const int end = lo;
  const int deg = end - start;

  float m = -3.4e38f;
  for (int i = tid; i < deg; i += 64) m = fmaxf(m, logits[start + i]);
#pragma unroll
  for (int off = 32; off; off >>= 1) m = fmaxf(m, __shfl_xor(m, off));

  float s = 0.f;
  for (int i = tid; i < deg; i += 64) s += __expf(logits[start + i] - m);
#pragma unroll
  for (int off = 32; off; off >>= 1) s += __shfl_xor(s, off);
  const float inv = (s > 0.f) ? (1.f / s) : 0.f;

  float2 acc = make_float2(0.f, 0.f);
  const float2* u2 = (const float2*)u2e;
  for (int c0 = 0; c0 < deg; c0 += 1024) {
    int cn = min(1024, deg - c0);
    __syncthreads();
    for (int i = tid; i < cn; i += 64)
      p_lds[i] = __expf(logits[start + c0 + i] - m);
    __syncthreads();
    for (int i = 0; i < cn; ++i) {
      float a = p_lds[i] * inv;
      float2 v = u2[(long)neigh_idx[start + c0 + i] * 64 + tid];
      acc.x = fmaf(a, v.x, acc.x);
      acc.y = fmaf(a, v.y, acc.y);
    }
  }
  ((float2*)out)[(long)b * 64 + tid] = acc;
}

extern "C" void kernel_launch(void* const* d_in, const int* in_sizes, int n_in,
                              void* d_out, int out_size, void* d_ws, size_t ws_size,
                              hipStream_t stream) {
  const int*   nodes     = (const int*)d_in[0];
  const int*   neigh_idx = (const int*)d_in[1];
  const int*   seg_ids   = (const int*)d_in[2];
  const float* u2e       = (const float*)d_in[3];
  const float* att1_w    = (const float*)d_in[4];
  const float* att1_b    = (const float*)d_in[5];
  const float* att2_w    = (const float*)d_in[6];
  const float* att2_b    = (const float*)d_in[7];
  const float* att3_w    = (const float*)d_in[8];
  const float* att3_b    = (const float*)d_in[9];
  const int B = in_sizes[0];
  const int E = in_sizes[1];

  float* y      = (float*)d_ws;                                    // B*128 floats
  float* logits = (float*)((char*)d_ws + (size_t)B * DDIM * 4);    // E floats

  node_term_kernel<<<(B + 7) / 8, 128, 0, stream>>>(nodes, u2e, att1_w, att1_b, y, B);
  logits_mfma_kernel<<<(E + TE - 1) / TE, 256, 65536, stream>>>(
      neigh_idx, seg_ids, u2e, att1_w, att2_w, att2_b, att3_w, att3_b, y, logits, E);
  softmax_agg_kernel<<<B, 64, 0, stream>>>(neigh_idx, seg_ids, u2e, logits,
                                           (float*)d_out, B, E);
}